// Round 10
// baseline (77.847 us; speedup 1.0000x reference)
//
#include <hip/hip_runtime.h>
#include <math.h>

#define NROWS 32768
#define DIM   64
#define NCODE 4096
#define EPS_RMS 1.1920929e-07f
#define EPS_BN  1e-5f

typedef _Float16 f16x8 __attribute__((ext_vector_type(8)));
typedef float    f32x4 __attribute__((ext_vector_type(4)));

// ws byte layout
#define WS_PS   0                          // partial sums  [64][64] f32
#define WS_PQ   16384                      // partial sumsq [64][64] f32
#define WS_CC   32768                      // ccn[4096] = -0.5*sum(c^2)
#define WS_CB32 49152                      // cb fp32 [4096][64] (for gather)
#define WS_PH   (49152 + 1048576)          // packed B-frag hi [256 grp][2 c][64 lane][16B]
#define WS_PL   (WS_PH + 524288)           // packed B-frag lo
#define WS_PART (WS_PL + 524288)           // (d, idx) partials [2][NROWS][2] f32

// out float offsets
#define OUT1 ((size_t)NROWS * DIM)           // z_e
#define OUT2 ((size_t)2 * NROWS * DIM)       // q
#define OUT3 (OUT2 + NROWS)                  // z_q

#define MFMA16(a, b, c) __builtin_amdgcn_mfma_f32_16x16x32_f16(a, b, c, 0, 0, 0)

__global__ __launch_bounds__(256) void k_bn1(const float* __restrict__ w,
                                             char* __restrict__ wsb) {
    __shared__ float s1[4][64], s2[4][64];
    int lane = threadIdx.x & 63, v = threadIdx.x >> 6;
    long base = (long)blockIdx.x * 64 + v * 16;
    float s = 0.f, sq = 0.f;
    #pragma unroll
    for (int i = 0; i < 16; i++) {
        float x = w[(base + i) * DIM + lane];
        s += x; sq += x * x;
    }
    s1[v][lane] = s; s2[v][lane] = sq;
    __syncthreads();
    if (threadIdx.x < 64) {
        float ts = s1[0][lane] + s1[1][lane] + s1[2][lane] + s1[3][lane];
        float tq = s2[0][lane] + s2[1][lane] + s2[2][lane] + s2[3][lane];
        ((float*)(wsb + WS_PS))[blockIdx.x * 64 + lane] = ts;
        ((float*)(wsb + WS_PQ))[blockIdx.x * 64 + lane] = tq;
    }
}

// one block = one 16-code group g: normalize, write cb32/ccn, emit packed B-frags
__global__ __launch_bounds__(256) void k_cb(const float* __restrict__ w,
                                            const float* __restrict__ bnw,
                                            const float* __restrict__ bnb,
                                            char* __restrict__ wsb) {
    __shared__ float s1[4][64], s2[4][64], af[64], bf[64];
    __shared__ _Float16 sh[16][64], sl[16][64];
    int t = threadIdx.x, lane = t & 63, v = t >> 6;
    const float* ps = (const float*)(wsb + WS_PS);
    const float* pq = (const float*)(wsb + WS_PQ);
    float s = 0.f, sq = 0.f;
    #pragma unroll
    for (int b = 0; b < 16; b++) {
        s  += ps[(v * 16 + b) * 64 + lane];
        sq += pq[(v * 16 + b) * 64 + lane];
    }
    s1[v][lane] = s; s2[v][lane] = sq;
    __syncthreads();
    if (t < 64) {
        float ts = s1[0][lane] + s1[1][lane] + s1[2][lane] + s1[3][lane];
        float tq = s2[0][lane] + s2[1][lane] + s2[2][lane] + s2[3][lane];
        float mean = ts * (1.0f / NCODE);
        float var  = tq * (1.0f / NCODE) - mean * mean;
        float a = rsqrtf(var + EPS_BN) * bnw[lane];
        af[lane] = a;
        bf[lane] = bnb[lane] - mean * a;
    }
    __syncthreads();
    float a = af[lane], bb = bf[lane];
    float* cb32 = (float*)(wsb + WS_CB32);
    float* ccp  = (float*)(wsb + WS_CC);
    int g = blockIdx.x;
    #pragma unroll
    for (int i = 0; i < 4; i++) {
        int  rl  = v * 4 + i;            // 0..15 within group
        long row = (long)g * 16 + rl;
        float x = w[row * DIM + lane];
        float h = fmaf(x, a, bb);
        float ss = h * h;
        #pragma unroll
        for (int m = 1; m < 64; m <<= 1) ss += __shfl_xor(ss, m);
        float rms = rsqrtf(ss * (1.0f / DIM) + EPS_RMS);
        float c = h * rms;
        cb32[row * DIM + lane] = c;
        _Float16 ch = (_Float16)c;
        sh[rl][lane] = ch;
        sl[rl][lane] = (_Float16)(c - (float)ch);
        float cs = c * c;
        #pragma unroll
        for (int m = 1; m < 64; m <<= 1) cs += __shfl_xor(cs, m);
        if (lane == 0) ccp[row] = -0.5f * cs;   // folded into MFMA C-init
    }
    __syncthreads();
    // packed B-frag emit: t>>7 = matrix (0 hi, 1 lo), u=t&127: c=u>>6, l=u&63
    {
        int u = t & 127;
        int c = u >> 6, l = u & 63;
        int codel = l & 15;
        int kbase = c * 32 + (l >> 4) * 8;
        size_t dst = (size_t)((g * 2 + c) * 64 + l) * 16;
        if (t < 128) {
            *(f16x8*)(wsb + WS_PH + dst) = *(const f16x8*)&sh[codel][kbase];
        } else {
            *(f16x8*)(wsb + WS_PL + dst) = *(const f16x8*)&sl[codel][kbase];
        }
    }
}

// ---- main: 1024 blocks = 512 rowblocks x 2 code-halves; 256 thr / 4 waves.
//      Wave = (row-half: 32 rows) x (code-quarter: 1024 codes of the half).
//      ~110 live regs/wave -> launch_bounds(256,4) WITHOUT spill (R7/R8 spilled
//      because 64-row waves carried ~165 live regs > 128 cap).
__global__ __launch_bounds__(256, 4) void k_main(const float* __restrict__ z,
                                                 char* __restrict__ wsb,
                                                 float* __restrict__ out) {
    __shared__ __align__(16) unsigned char sm[18432];
    // zh f16[64][64] @0 (8KB), zl @8192; redd@16384 [64][2], redi@16896 [64][2]

    const int tid  = threadIdx.x;
    const int lane = tid & 63;
    const int wv   = tid >> 6;      // wave 0..3
    const int wrh  = wv >> 1;       // row half (32 rows)
    const int wq   = wv & 1;        // code quarter within this block's half
    const int l15  = lane & 15;
    const int l4   = lane >> 4;
    const int rowblk = blockIdx.x >> 1;
    const int half   = blockIdx.x & 1;
    const long rowbase = (long)rowblk * 64;

    const float* ccnG = (const float*)(wsb + WS_CC);

    // ---- prologue: RMS-norm 64 rows of z, write z_e (half 0), hi/lo split to LDS
    {
        int r = tid >> 2, seg = tid & 3;   // 16 floats per thread
        const float4* zp = (const float4*)(z + (rowbase + r) * DIM + seg * 16);
        float4 v4[4];
        float ss = 0.f;
        #pragma unroll
        for (int i = 0; i < 4; i++) {
            v4[i] = zp[i];
            ss += v4[i].x * v4[i].x + v4[i].y * v4[i].y + v4[i].z * v4[i].z + v4[i].w * v4[i].w;
        }
        ss += __shfl_xor(ss, 1);
        ss += __shfl_xor(ss, 2);
        float rms = rsqrtf(ss * (1.0f / DIM) + EPS_RMS);
        float4* oz = (float4*)(out + OUT1 + (rowbase + r) * DIM + seg * 16);
        __align__(16) _Float16 hb[16], lb[16];
        #pragma unroll
        for (int i = 0; i < 4; i++) {
            float xs[4] = {v4[i].x, v4[i].y, v4[i].z, v4[i].w};
            #pragma unroll
            for (int j = 0; j < 4; j++) {
                float x = xs[j] * rms;
                _Float16 h = (_Float16)x;
                hb[i * 4 + j] = h;
                lb[i * 4 + j] = (_Float16)(x - (float)h);
                xs[j] = x;
            }
            if (half == 0) oz[i] = make_float4(xs[0], xs[1], xs[2], xs[3]);
        }
        unsigned char* zhp = sm + r * 128 + seg * 32;
        ((f16x8*)zhp)[0] = ((f16x8*)hb)[0];
        ((f16x8*)zhp)[1] = ((f16x8*)hb)[1];
        unsigned char* zlp = zhp + 8192;
        ((f16x8*)zlp)[0] = ((f16x8*)lb)[0];
        ((f16x8*)zlp)[1] = ((f16x8*)lb)[1];
    }
    __syncthreads();

    // ---- A fragments: 2 row-subtiles x 2 k-chunks, hi+lo (32 VGPR)
    f16x8 ah[2][2], al[2][2];
    #pragma unroll
    for (int s = 0; s < 2; s++)
        #pragma unroll
        for (int c = 0; c < 2; c++) {
            int off = (wrh * 32 + s * 16 + l15) * 128 + c * 64 + l4 * 16;
            ah[s][c] = *(const f16x8*)(sm + off);
            al[s][c] = *(const f16x8*)(sm + 8192 + off);
        }

    float bmax[2][4];
    int   bix[2][4];
    #pragma unroll
    for (int s = 0; s < 2; s++)
        #pragma unroll
        for (int r = 0; r < 4; r++) { bmax[s][r] = -3.4e38f; bix[s][r] = 0; }

    // B-stream: wave scans 64 groups = 1024 codes (quarter wq of this half)
    const int gw = half * 128 + wq * 64;       // group units
    const char* pH = wsb + WS_PH + (size_t)(gw * 2) * 1024 + lane * 16;
    const char* pL = wsb + WS_PL + (size_t)(gw * 2) * 1024 + lane * 16;
    const float* cn = ccnG + gw * 16 + l15;

    #define LOADB(H0, H1, L0, L1, CC, k)                       \
        H0 = *(const f16x8*)(pH + (size_t)(k) * 2048);         \
        H1 = *(const f16x8*)(pH + (size_t)(k) * 2048 + 1024);  \
        L0 = *(const f16x8*)(pL + (size_t)(k) * 2048);         \
        L1 = *(const f16x8*)(pL + (size_t)(k) * 2048 + 1024);  \
        CC = cn[(k) * 16];

    #define COMPUTE(H0, H1, L0, L1, CC, k)                                        \
    {                                                                             \
        int code = (gw + (k)) * 16 + l15;                                         \
        _Pragma("unroll")                                                         \
        for (int s = 0; s < 2; s++) {                                             \
            f32x4 a2 = {CC, CC, CC, CC};                                          \
            a2 = MFMA16(ah[s][0], H0, a2);                                        \
            a2 = MFMA16(ah[s][1], H1, a2);                                        \
            a2 = MFMA16(ah[s][0], L0, a2);                                        \
            a2 = MFMA16(ah[s][1], L1, a2);                                        \
            a2 = MFMA16(al[s][0], H0, a2);                                        \
            a2 = MFMA16(al[s][1], H1, a2);                                        \
            _Pragma("unroll")                                                     \
            for (int r = 0; r < 4; r++) {                                         \
                if (a2[r] > bmax[s][r]) { bmax[s][r] = a2[r]; bix[s][r] = code; } \
            }                                                                     \
        }                                                                         \
    }

    f16x8 hA0, hA1, lA0, lA1, hB0, hB1, lB0, lB1;
    float ccA, ccB;
    LOADB(hA0, hA1, lA0, lA1, ccA, 0);
    #pragma unroll 1
    for (int k = 0; k < 62; k += 2) {
        LOADB(hB0, hB1, lB0, lB1, ccB, k + 1);
        COMPUTE(hA0, hA1, lA0, lA1, ccA, k);
        LOADB(hA0, hA1, lA0, lA1, ccA, k + 2);
        COMPUTE(hB0, hB1, lB0, lB1, ccB, k + 1);
    }
    LOADB(hB0, hB1, lB0, lB1, ccB, 63);
    COMPUTE(hA0, hA1, lA0, lA1, ccA, 62);
    COMPUTE(hB0, hB1, lB0, lB1, ccB, 63);

    // ---- reduce: 16 code-lanes, then the 2 quarter-waves per row; write partial
    float* redd = (float*)(sm + 16384);   // [64][2]
    int*   redi = (int*)(sm + 16896);     // [64][2]
    #pragma unroll
    for (int s = 0; s < 2; s++)
        #pragma unroll
        for (int r = 0; r < 4; r++) {
            float d = bmax[s][r];
            int   ix = bix[s][r];
            #pragma unroll
            for (int m = 1; m < 16; m <<= 1) {
                float od = __shfl_xor(d, m);
                int   oi = __shfl_xor(ix, m);
                if (od > d || (od == d && oi < ix)) { d = od; ix = oi; }
            }
            if (l15 == 0) {
                int row = wrh * 32 + s * 16 + l4 * 4 + r;
                redd[row * 2 + wq] = d;
                redi[row * 2 + wq] = ix;
            }
        }
    __syncthreads();
    if (tid < 64) {
        float d0 = redd[tid * 2 + 0];
        int   i0 = redi[tid * 2 + 0];
        float d1 = redd[tid * 2 + 1];
        int   i1 = redi[tid * 2 + 1];
        // quarter 0 has lower codes: prefer it on ties
        float bv = d0; int bi_ = i0;
        if (d1 > bv || (d1 == bv && i1 < bi_)) { bv = d1; bi_ = i1; }
        float* part = (float*)(wsb + WS_PART);
        size_t off = ((size_t)half * NROWS + rowbase + tid) * 2;
        part[off]     = bv;
        part[off + 1] = (float)bi_;
    }
}

// ---- combine 2 half-partials, write q + gather cb32 -> chunk0/chunk3
__global__ __launch_bounds__(256) void k_final(const char* __restrict__ wsb,
                                               float* __restrict__ out) {
    int gid = blockIdx.x * 256 + threadIdx.x;
    int r   = gid >> 3;
    int seg = gid & 7;
    const float* part = (const float*)(wsb + WS_PART);
    const float* cb32 = (const float*)(wsb + WS_CB32);
    float d0 = part[(size_t)r * 2],           i0f = part[(size_t)r * 2 + 1];
    float d1 = part[((size_t)NROWS + r) * 2], i1f = part[((size_t)NROWS + r) * 2 + 1];
    int i0 = (int)i0f, i1 = (int)i1f;
    int best = (d1 > d0 || (d1 == d0 && i1 < i0)) ? i1 : i0;
    const float4* src = (const float4*)(cb32 + (long)best * DIM + seg * 8);
    float4* o0 = (float4*)(out + (size_t)r * DIM + seg * 8);
    float4* o3 = (float4*)(out + OUT3 + (size_t)r * DIM + seg * 8);
    #pragma unroll
    for (int i = 0; i < 2; i++) { float4 t4 = src[i]; o0[i] = t4; o3[i] = t4; }
    if (seg == 0) out[OUT2 + r] = (float)best;
}

extern "C" void kernel_launch(void* const* d_in, const int* in_sizes, int n_in,
                              void* d_out, int out_size, void* d_ws, size_t ws_size,
                              hipStream_t stream) {
    const float* z   = (const float*)d_in[0];
    const float* w   = (const float*)d_in[1];
    const float* bnw = (const float*)d_in[2];
    const float* bnb = (const float*)d_in[3];
    float* out = (float*)d_out;
    char*  wsb = (char*)d_ws;

    k_bn1  <<<64,   256, 0, stream>>>(w, wsb);
    k_cb   <<<256,  256, 0, stream>>>(w, bnw, bnb, wsb);
    k_main <<<1024, 256, 0, stream>>>(z, wsb, out);
    k_final<<<NROWS * 8 / 256, 256, 0, stream>>>(wsb, out);
}

// Round 11
// 75.878 us; speedup vs baseline: 1.0259x; 1.0259x over previous
//
#include <hip/hip_runtime.h>
#include <math.h>

#define NROWS 32768
#define DIM   64
#define NCODE 4096
#define EPS_RMS 1.1920929e-07f
#define EPS_BN  1e-5f

typedef _Float16 f16x8 __attribute__((ext_vector_type(8)));
typedef float    f32x4 __attribute__((ext_vector_type(4)));

// ws byte layout
#define WS_PS   0                          // partial sums  [64][64] f32
#define WS_PQ   16384                      // partial sumsq [64][64] f32
#define WS_CC   32768                      // ccn[4096] = -0.5*sum(c^2)
#define WS_CB32 49152                      // cb fp32 [4096][64] (for gather)
#define WS_PH   (49152 + 1048576)          // packed B-frag hi [256 grp][2 c][64 lane][16B]
#define WS_PL   (WS_PH + 524288)           // packed B-frag lo

// out float offsets
#define OUT1 ((size_t)NROWS * DIM)           // z_e
#define OUT2 ((size_t)2 * NROWS * DIM)       // q
#define OUT3 (OUT2 + NROWS)                  // z_q

#define MFMA16(a, b, c) __builtin_amdgcn_mfma_f32_16x16x32_f16(a, b, c, 0, 0, 0)

__device__ __forceinline__ void gload16(void* lds, const void* g) {
    __builtin_amdgcn_global_load_lds(
        (const __attribute__((address_space(1))) unsigned int*)g,
        (__attribute__((address_space(3))) unsigned int*)lds, 16, 0, 0);
}

__global__ __launch_bounds__(256) void k_bn1(const float* __restrict__ w,
                                             char* __restrict__ wsb) {
    __shared__ float s1[4][64], s2[4][64];
    int lane = threadIdx.x & 63, v = threadIdx.x >> 6;
    long base = (long)blockIdx.x * 64 + v * 16;
    float s = 0.f, sq = 0.f;
    #pragma unroll
    for (int i = 0; i < 16; i++) {
        float x = w[(base + i) * DIM + lane];
        s += x; sq += x * x;
    }
    s1[v][lane] = s; s2[v][lane] = sq;
    __syncthreads();
    if (threadIdx.x < 64) {
        float ts = s1[0][lane] + s1[1][lane] + s1[2][lane] + s1[3][lane];
        float tq = s2[0][lane] + s2[1][lane] + s2[2][lane] + s2[3][lane];
        ((float*)(wsb + WS_PS))[blockIdx.x * 64 + lane] = ts;
        ((float*)(wsb + WS_PQ))[blockIdx.x * 64 + lane] = tq;
    }
}

// one block = one 16-code group g: normalize, write cb32/ccn, emit packed B-frags
__global__ __launch_bounds__(256) void k_cb(const float* __restrict__ w,
                                            const float* __restrict__ bnw,
                                            const float* __restrict__ bnb,
                                            char* __restrict__ wsb) {
    __shared__ float s1[4][64], s2[4][64], af[64], bf[64];
    __shared__ _Float16 sh[16][64], sl[16][64];
    int t = threadIdx.x, lane = t & 63, v = t >> 6;
    const float* ps = (const float*)(wsb + WS_PS);
    const float* pq = (const float*)(wsb + WS_PQ);
    float s = 0.f, sq = 0.f;
    #pragma unroll
    for (int b = 0; b < 16; b++) {
        s  += ps[(v * 16 + b) * 64 + lane];
        sq += pq[(v * 16 + b) * 64 + lane];
    }
    s1[v][lane] = s; s2[v][lane] = sq;
    __syncthreads();
    if (t < 64) {
        float ts = s1[0][lane] + s1[1][lane] + s1[2][lane] + s1[3][lane];
        float tq = s2[0][lane] + s2[1][lane] + s2[2][lane] + s2[3][lane];
        float mean = ts * (1.0f / NCODE);
        float var  = tq * (1.0f / NCODE) - mean * mean;
        float a = rsqrtf(var + EPS_BN) * bnw[lane];
        af[lane] = a;
        bf[lane] = bnb[lane] - mean * a;
    }
    __syncthreads();
    float a = af[lane], bb = bf[lane];
    float* cb32 = (float*)(wsb + WS_CB32);
    float* ccp  = (float*)(wsb + WS_CC);
    int g = blockIdx.x;
    #pragma unroll
    for (int i = 0; i < 4; i++) {
        int  rl  = v * 4 + i;            // 0..15 within group
        long row = (long)g * 16 + rl;
        float x = w[row * DIM + lane];
        float h = fmaf(x, a, bb);
        float ss = h * h;
        #pragma unroll
        for (int m = 1; m < 64; m <<= 1) ss += __shfl_xor(ss, m);
        float rms = rsqrtf(ss * (1.0f / DIM) + EPS_RMS);
        float c = h * rms;
        cb32[row * DIM + lane] = c;
        _Float16 ch = (_Float16)c;
        sh[rl][lane] = ch;
        sl[rl][lane] = (_Float16)(c - (float)ch);
        float cs = c * c;
        #pragma unroll
        for (int m = 1; m < 64; m <<= 1) cs += __shfl_xor(cs, m);
        if (lane == 0) ccp[row] = -0.5f * cs;   // folded into MFMA C-init
    }
    __syncthreads();
    // packed B-frag emit: t>>7 = matrix (0 hi, 1 lo), u=t&127: c=u>>6, l=u&63
    {
        int u = t & 127;
        int c = u >> 6, l = u & 63;
        int codel = l & 15;
        int kbase = c * 32 + (l >> 4) * 8;
        size_t dst = (size_t)((g * 2 + c) * 64 + l) * 16;
        if (t < 128) {
            *(f16x8*)(wsb + WS_PH + dst) = *(const f16x8*)&sh[codel][kbase];
        } else {
            *(f16x8*)(wsb + WS_PL + dst) = *(const f16x8*)&sl[codel][kbase];
        }
    }
}

// ---- main: 256 blocks (1/CU) x 512 thr / 8 waves; 128 rows/block, all 4096 codes.
//      L2-BW-bound fix: B-traffic = 256 blocks x 1MB = 256MB (half of R6-R10's 512MB).
//      Wave = (row-group rg: 32 rows) x (code-half ch: 64 of the 128-code pass tile).
//      B staged in shared LDS (32KB/pass, dbuf) via global_load_lds of the packed
//      fragment stream -> per-lane contiguous ds_read_b128, zero conflicts.
__global__ __launch_bounds__(512, 2) void k_main(const float* __restrict__ z,
                                                 char* __restrict__ wsb,
                                                 float* __restrict__ out) {
    // LDS map: buf0 @0 (hi 16K, lo 16K), buf1 @32768; zh @65536 (16K), zl @81920 (16K)
    // reduce scratch reuses buf0 region at the end.
    __shared__ __align__(16) unsigned char sm[98304];

    const int tid  = threadIdx.x;
    const int lane = tid & 63;
    const int w    = tid >> 6;      // wave 0..7
    const int rg   = w & 3;         // row group (32 rows)
    const int ch   = w >> 2;        // code half of the pass tile (64 codes)
    const int l15  = lane & 15;
    const int l4   = lane >> 4;
    const long rowbase = (long)blockIdx.x * 128;

    const float* ccnG = (const float*)(wsb + WS_CC);
    const float* cb32 = (const float*)(wsb + WS_CB32);

    // running global pointers for staging (pass-invariant per-lane part)
    const char* pH = wsb + WS_PH + w * 1024 + lane * 16;
    const char* pL = wsb + WS_PL + w * 1024 + lane * 16;

    #define STAGE(p, bufoff)                                                \
    {                                                                       \
        const char* gh = pH + (size_t)(p) * 16384;                          \
        const char* gl = pL + (size_t)(p) * 16384;                          \
        gload16(sm + (bufoff) + w * 1024,          gh);                     \
        gload16(sm + (bufoff) + 8192 + w * 1024,   gh + 8192);              \
        gload16(sm + (bufoff) + 16384 + w * 1024,  gl);                     \
        gload16(sm + (bufoff) + 24576 + w * 1024,  gl + 8192);              \
    }

    // ---- stage pass 0 into buf0 (overlaps z prologue)
    STAGE(0, 0);

    // ---- prologue: RMS-norm 128 rows of z, write z_e, hi/lo split into zh/zl LDS
    {
        int r = tid >> 2, seg = tid & 3;   // 16 floats per thread, r = 0..127
        const float4* zp = (const float4*)(z + (rowbase + r) * DIM + seg * 16);
        float4 v4[4];
        float ss = 0.f;
        #pragma unroll
        for (int i = 0; i < 4; i++) {
            v4[i] = zp[i];
            ss += v4[i].x * v4[i].x + v4[i].y * v4[i].y + v4[i].z * v4[i].z + v4[i].w * v4[i].w;
        }
        ss += __shfl_xor(ss, 1);
        ss += __shfl_xor(ss, 2);
        float rms = rsqrtf(ss * (1.0f / DIM) + EPS_RMS);
        float4* oz = (float4*)(out + OUT1 + (rowbase + r) * DIM + seg * 16);
        __align__(16) _Float16 hb[16], lb[16];
        #pragma unroll
        for (int i = 0; i < 4; i++) {
            float xs[4] = {v4[i].x, v4[i].y, v4[i].z, v4[i].w};
            #pragma unroll
            for (int j = 0; j < 4; j++) {
                float x = xs[j] * rms;
                _Float16 h = (_Float16)x;
                hb[i * 4 + j] = h;
                lb[i * 4 + j] = (_Float16)(x - (float)h);
                xs[j] = x;
            }
            oz[i] = make_float4(xs[0], xs[1], xs[2], xs[3]);
        }
        unsigned char* zhp = sm + 65536 + r * 128 + seg * 32;
        ((f16x8*)zhp)[0] = ((f16x8*)hb)[0];
        ((f16x8*)zhp)[1] = ((f16x8*)hb)[1];
        unsigned char* zlp = zhp + 16384;
        ((f16x8*)zlp)[0] = ((f16x8*)lb)[0];
        ((f16x8*)zlp)[1] = ((f16x8*)lb)[1];
    }
    __syncthreads();   // zh/zl ready AND buf0 staged (vmcnt drained)

    // ---- A fragments: 2 row-subtiles x 2 k-chunks, hi+lo (32 VGPR)
    f16x8 ah[2][2], al[2][2];
    #pragma unroll
    for (int s = 0; s < 2; s++)
        #pragma unroll
        for (int c = 0; c < 2; c++) {
            int off = 65536 + (rg * 32 + s * 16 + l15) * 128 + c * 64 + l4 * 16;
            ah[s][c] = *(const f16x8*)(sm + off);
            al[s][c] = *(const f16x8*)(sm + 16384 + off);
        }

    float bmax[2][4];
    int   bix[2][4];
    #pragma unroll
    for (int s = 0; s < 2; s++)
        #pragma unroll
        for (int r = 0; r < 4; r++) { bmax[s][r] = -3.4e38f; bix[s][r] = 0; }

    // cc for pass 0
    float ccv[4];
    #pragma unroll
    for (int q = 0; q < 4; q++)
        ccv[q] = ccnG[ch * 64 + q * 16 + l15];

    #define COMPUTE(p, bufoff)                                                     \
    {                                                                              \
        _Pragma("unroll")                                                          \
        for (int q = 0; q < 4; q++) {                                              \
            f16x8 bh[2], bl[2];                                                    \
            _Pragma("unroll")                                                      \
            for (int c = 0; c < 2; c++) {                                          \
                int boff = (bufoff) + (ch * 8 + q * 2 + c) * 1024 + lane * 16;     \
                bh[c] = *(const f16x8*)(sm + boff);                                \
                bl[c] = *(const f16x8*)(sm + 16384 + boff);                        \
            }                                                                      \
            int code = (p) * 128 + ch * 64 + q * 16 + l15;                         \
            _Pragma("unroll")                                                      \
            for (int s = 0; s < 2; s++) {                                          \
                f32x4 a2 = {ccv[q], ccv[q], ccv[q], ccv[q]};                       \
                a2 = MFMA16(ah[s][0], bh[0], a2);                                  \
                a2 = MFMA16(ah[s][1], bh[1], a2);                                  \
                a2 = MFMA16(ah[s][0], bl[0], a2);                                  \
                a2 = MFMA16(ah[s][1], bl[1], a2);                                  \
                a2 = MFMA16(al[s][0], bh[0], a2);                                  \
                a2 = MFMA16(al[s][1], bh[1], a2);                                  \
                _Pragma("unroll")                                                  \
                for (int r = 0; r < 4; r++) {                                      \
                    if (a2[r] > bmax[s][r]) { bmax[s][r] = a2[r]; bix[s][r] = code; } \
                }                                                                  \
            }                                                                      \
        }                                                                          \
    }

    #pragma unroll 1
    for (int p = 0; p < 31; ++p) {
        // stage pass p+1 into the other buffer + prefetch its cc (flies under compute)
        STAGE(p + 1, ((p + 1) & 1) * 32768);
        float ccn_nx[4];
        {
            const float* cn = ccnG + (p + 1) * 128 + ch * 64 + l15;
            #pragma unroll
            for (int q = 0; q < 4; q++) ccn_nx[q] = cn[q * 16];
        }

        COMPUTE(p, (p & 1) * 32768);

        __syncthreads();   // drains staging; closes reads of current buffer
        #pragma unroll
        for (int q = 0; q < 4; q++) ccv[q] = ccn_nx[q];
    }
    COMPUTE(31, 32768);

    // ---- argmax reduce: 16 code-lanes, then the 2 code-half waves per row
    float* redd = (float*)sm;            // [128][2]  (reuses buf0, disjoint from buf1)
    int*   redi = (int*)(sm + 1024);     // [128][2]
    int*   bidx = (int*)(sm + 2048);     // [128]
    #pragma unroll
    for (int s = 0; s < 2; s++)
        #pragma unroll
        for (int r = 0; r < 4; r++) {
            float d = bmax[s][r];
            int   ix = bix[s][r];
            #pragma unroll
            for (int m = 1; m < 16; m <<= 1) {
                float od = __shfl_xor(d, m);
                int   oi = __shfl_xor(ix, m);
                if (od > d || (od == d && oi < ix)) { d = od; ix = oi; }
            }
            if (l15 == 0) {
                int row = rg * 32 + s * 16 + l4 * 4 + r;
                redd[row * 2 + ch] = d;
                redi[row * 2 + ch] = ix;
            }
        }
    __syncthreads();
    if (tid < 128) {
        float d0 = redd[tid * 2 + 0];
        int   i0 = redi[tid * 2 + 0];
        float d1 = redd[tid * 2 + 1];
        int   i1 = redi[tid * 2 + 1];
        // half 0 has lower codes: prefer it on ties
        float bv = d0; int bi_ = i0;
        if (d1 > bv || (d1 == bv && i1 < bi_)) { bv = d1; bi_ = i1; }
        bidx[tid] = bi_;
        out[OUT2 + rowbase + tid] = (float)bi_;
    }
    __syncthreads();
    {   // gather cb32[best] -> chunk0 and chunk3
        int r = tid >> 2, seg = tid & 3;
        int ix = bidx[r];
        const float4* src = (const float4*)(cb32 + (long)ix * DIM + seg * 16);
        float4* o0 = (float4*)(out + (rowbase + r) * DIM + seg * 16);
        float4* o3 = (float4*)(out + OUT3 + (rowbase + r) * DIM + seg * 16);
        #pragma unroll
        for (int i = 0; i < 4; i++) { float4 t4 = src[i]; o0[i] = t4; o3[i] = t4; }
    }
}

extern "C" void kernel_launch(void* const* d_in, const int* in_sizes, int n_in,
                              void* d_out, int out_size, void* d_ws, size_t ws_size,
                              hipStream_t stream) {
    const float* z   = (const float*)d_in[0];
    const float* w   = (const float*)d_in[1];
    const float* bnw = (const float*)d_in[2];
    const float* bnb = (const float*)d_in[3];
    float* out = (float*)d_out;
    char*  wsb = (char*)d_ws;

    k_bn1 <<<64,  256, 0, stream>>>(w, wsb);
    k_cb  <<<256, 256, 0, stream>>>(w, bnw, bnb, wsb);
    k_main<<<256, 512, 0, stream>>>(z, wsb, out);
}

// Round 12
// 74.937 us; speedup vs baseline: 1.0388x; 1.0126x over previous
//
#include <hip/hip_runtime.h>
#include <math.h>

#define NROWS 32768
#define DIM   64
#define NCODE 4096
#define EPS_RMS 1.1920929e-07f
#define EPS_BN  1e-5f

typedef _Float16 f16x8 __attribute__((ext_vector_type(8)));
typedef float    f32x4 __attribute__((ext_vector_type(4)));

// ws byte layout
#define WS_PS   0                          // partial sums  [64][64] f32
#define WS_PQ   16384                      // partial sumsq [64][64] f32
#define WS_CC   32768                      // ccn[4096] = -0.5*sum(c^2)
#define WS_CB32 49152                      // cb fp32 [4096][64] (for gather)
#define WS_PH   (49152 + 1048576)          // packed B-frag hi [256 grp][2 c][64 lane][16B]
#define WS_PL   (WS_PH + 524288)           // packed B-frag lo

// out float offsets
#define OUT1 ((size_t)NROWS * DIM)           // z_e
#define OUT2 ((size_t)2 * NROWS * DIM)       // q
#define OUT3 (OUT2 + NROWS)                  // z_q

#define MFMA16(a, b, c) __builtin_amdgcn_mfma_f32_16x16x32_f16(a, b, c, 0, 0, 0)

__device__ __forceinline__ void gload16(void* lds, const void* g) {
    __builtin_amdgcn_global_load_lds(
        (const __attribute__((address_space(1))) unsigned int*)g,
        (__attribute__((address_space(3))) unsigned int*)lds, 16, 0, 0);
}

__global__ __launch_bounds__(256) void k_bn1(const float* __restrict__ w,
                                             char* __restrict__ wsb) {
    __shared__ float s1[4][64], s2[4][64];
    int lane = threadIdx.x & 63, v = threadIdx.x >> 6;
    long base = (long)blockIdx.x * 64 + v * 16;
    float s = 0.f, sq = 0.f;
    #pragma unroll
    for (int i = 0; i < 16; i++) {
        float x = w[(base + i) * DIM + lane];
        s += x; sq += x * x;
    }
    s1[v][lane] = s; s2[v][lane] = sq;
    __syncthreads();
    if (threadIdx.x < 64) {
        float ts = s1[0][lane] + s1[1][lane] + s1[2][lane] + s1[3][lane];
        float tq = s2[0][lane] + s2[1][lane] + s2[2][lane] + s2[3][lane];
        ((float*)(wsb + WS_PS))[blockIdx.x * 64 + lane] = ts;
        ((float*)(wsb + WS_PQ))[blockIdx.x * 64 + lane] = tq;
    }
}

// one block = one 16-code group g: normalize, write cb32/ccn, emit packed B-frags
__global__ __launch_bounds__(256) void k_cb(const float* __restrict__ w,
                                            const float* __restrict__ bnw,
                                            const float* __restrict__ bnb,
                                            char* __restrict__ wsb) {
    __shared__ float s1[4][64], s2[4][64], af[64], bf[64];
    __shared__ _Float16 sh[16][64], sl[16][64];
    int t = threadIdx.x, lane = t & 63, v = t >> 6;
    const float* ps = (const float*)(wsb + WS_PS);
    const float* pq = (const float*)(wsb + WS_PQ);
    float s = 0.f, sq = 0.f;
    #pragma unroll
    for (int b = 0; b < 16; b++) {
        s  += ps[(v * 16 + b) * 64 + lane];
        sq += pq[(v * 16 + b) * 64 + lane];
    }
    s1[v][lane] = s; s2[v][lane] = sq;
    __syncthreads();
    if (t < 64) {
        float ts = s1[0][lane] + s1[1][lane] + s1[2][lane] + s1[3][lane];
        float tq = s2[0][lane] + s2[1][lane] + s2[2][lane] + s2[3][lane];
        float mean = ts * (1.0f / NCODE);
        float var  = tq * (1.0f / NCODE) - mean * mean;
        float a = rsqrtf(var + EPS_BN) * bnw[lane];
        af[lane] = a;
        bf[lane] = bnb[lane] - mean * a;
    }
    __syncthreads();
    float a = af[lane], bb = bf[lane];
    float* cb32 = (float*)(wsb + WS_CB32);
    float* ccp  = (float*)(wsb + WS_CC);
    int g = blockIdx.x;
    #pragma unroll
    for (int i = 0; i < 4; i++) {
        int  rl  = v * 4 + i;            // 0..15 within group
        long row = (long)g * 16 + rl;
        float x = w[row * DIM + lane];
        float h = fmaf(x, a, bb);
        float ss = h * h;
        #pragma unroll
        for (int m = 1; m < 64; m <<= 1) ss += __shfl_xor(ss, m);
        float rms = rsqrtf(ss * (1.0f / DIM) + EPS_RMS);
        float c = h * rms;
        cb32[row * DIM + lane] = c;
        _Float16 ch = (_Float16)c;
        sh[rl][lane] = ch;
        sl[rl][lane] = (_Float16)(c - (float)ch);
        float cs = c * c;
        #pragma unroll
        for (int m = 1; m < 64; m <<= 1) cs += __shfl_xor(cs, m);
        if (lane == 0) ccp[row] = -0.5f * cs;   // folded into MFMA C-init
    }
    __syncthreads();
    // packed B-frag emit: t>>7 = matrix (0 hi, 1 lo), u=t&127: c=u>>6, l=u&63
    {
        int u = t & 127;
        int c = u >> 6, l = u & 63;
        int codel = l & 15;
        int kbase = c * 32 + (l >> 4) * 8;
        size_t dst = (size_t)((g * 2 + c) * 64 + l) * 16;
        if (t < 128) {
            *(f16x8*)(wsb + WS_PH + dst) = *(const f16x8*)&sh[codel][kbase];
        } else {
            *(f16x8*)(wsb + WS_PL + dst) = *(const f16x8*)&sl[codel][kbase];
        }
    }
}

// ---- main: 256 blocks (1/CU) x 512 thr / 8 waves; 128 rows/block, all 4096 codes.
//      T3/T4/T5 schedule: 64-code tiles through a 4-deep LDS ring fed by
//      global_load_lds; counted s_waitcnt vmcnt(4) (never 0 in-loop) + raw
//      s_barrier per tile; setprio(1) around the MFMA cluster.
//      LDS: ring 4x16KB @0, zh 16K @65536, zl 16K @81920, ccn 16K @98304.
__global__ __launch_bounds__(512, 2) void k_main(const float* __restrict__ z,
                                                 char* __restrict__ wsb,
                                                 float* __restrict__ out) {
    __shared__ __align__(16) unsigned char sm[114688];

    const int tid  = threadIdx.x;
    const int lane = tid & 63;
    const int w    = tid >> 6;      // wave 0..7
    const int rg   = w >> 1;        // row group (32 rows)
    const int ch   = w & 1;         // code half of each 64-code tile (32 codes)
    const int l15  = lane & 15;
    const int l4   = lane >> 4;
    const long rowbase = (long)blockIdx.x * 128;

    const float* cb32 = (const float*)(wsb + WS_CB32);

    // STAGE tile t (codes t*64..+64): 2 gload16/thread; LDS base wave-uniform,
    // global src per-lane; packed stream is linear so no swizzle needed.
    #define RING(t) (((t) & 3) * 16384)
    #define STAGE(t)                                                              \
    {                                                                             \
        const char* gh_ = wsb + WS_PH + (size_t)(t) * 8192 + (w * 1024 + lane * 16); \
        const char* gl_ = wsb + WS_PL + (size_t)(t) * 8192 + (w * 1024 + lane * 16); \
        gload16(sm + RING(t) + w * 1024,        gh_);                             \
        gload16(sm + RING(t) + 8192 + w * 1024, gl_);                             \
    }

    // ---- prologue: stage tiles 0..2 + ccn table (these drain at the one
    //      prologue __syncthreads; loop itself never drains vmcnt to 0)
    STAGE(0); STAGE(1); STAGE(2);
    {
        const char* gc = wsb + WS_CC + (w * 1024 + lane * 16);
        gload16(sm + 98304 + w * 1024, gc);
        gload16(sm + 98304 + 8192 + w * 1024, gc + 8192);
    }

    // ---- RMS-norm 128 rows of z, write z_e, hi/lo split into LDS
    {
        int r = tid >> 2, seg = tid & 3;   // 16 floats per thread
        const float4* zp = (const float4*)(z + (rowbase + r) * DIM + seg * 16);
        float4 v4[4];
        float ss = 0.f;
        #pragma unroll
        for (int i = 0; i < 4; i++) {
            v4[i] = zp[i];
            ss += v4[i].x * v4[i].x + v4[i].y * v4[i].y + v4[i].z * v4[i].z + v4[i].w * v4[i].w;
        }
        ss += __shfl_xor(ss, 1);
        ss += __shfl_xor(ss, 2);
        float rms = rsqrtf(ss * (1.0f / DIM) + EPS_RMS);
        float4* oz = (float4*)(out + OUT1 + (rowbase + r) * DIM + seg * 16);
        __align__(16) _Float16 hb[16], lb[16];
        #pragma unroll
        for (int i = 0; i < 4; i++) {
            float xs[4] = {v4[i].x, v4[i].y, v4[i].z, v4[i].w};
            #pragma unroll
            for (int j = 0; j < 4; j++) {
                float x = xs[j] * rms;
                _Float16 h = (_Float16)x;
                hb[i * 4 + j] = h;
                lb[i * 4 + j] = (_Float16)(x - (float)h);
                xs[j] = x;
            }
            oz[i] = make_float4(xs[0], xs[1], xs[2], xs[3]);
        }
        unsigned char* zhp = sm + 65536 + r * 128 + seg * 32;
        ((f16x8*)zhp)[0] = ((f16x8*)hb)[0];
        ((f16x8*)zhp)[1] = ((f16x8*)hb)[1];
        unsigned char* zlp = zhp + 16384;
        ((f16x8*)zlp)[0] = ((f16x8*)lb)[0];
        ((f16x8*)zlp)[1] = ((f16x8*)lb)[1];
    }
    __syncthreads();   // one full drain: tiles 0-2, ccn, z all resident

    // ---- A fragments: 2 row-subtiles x 2 k-chunks, hi+lo (32 VGPR)
    f16x8 ah[2][2], al[2][2];
    #pragma unroll
    for (int s = 0; s < 2; s++)
        #pragma unroll
        for (int c = 0; c < 2; c++) {
            int off = 65536 + (rg * 32 + s * 16 + l15) * 128 + c * 64 + l4 * 16;
            ah[s][c] = *(const f16x8*)(sm + off);
            al[s][c] = *(const f16x8*)(sm + 16384 + off);
        }

    float bmax[2][4];
    int   bix[2][4];
    #pragma unroll
    for (int s = 0; s < 2; s++)
        #pragma unroll
        for (int r = 0; r < 4; r++) { bmax[s][r] = -3.4e38f; bix[s][r] = 0; }

    #pragma unroll 1
    for (int t = 0; t < 64; ++t) {
        if (t + 3 < 64) STAGE(t + 3);

        const unsigned char* buf = sm + RING(t);
        // ccn from LDS (lgkm only; data-dep orders it before MFMA C-init)
        float ccv[2];
        ccv[0] = *(const float*)(sm + 98304 + (size_t)(t * 64 + ch * 32 + l15) * 4);
        ccv[1] = *(const float*)(sm + 98304 + (size_t)(t * 64 + ch * 32 + 16 + l15) * 4);

        f16x8 bh[2][2], bl[2][2];
        #pragma unroll
        for (int q = 0; q < 2; q++)
            #pragma unroll
            for (int c = 0; c < 2; c++) {
                int gl_ = (ch * 2 + q) * 2 + c;   // group-local frag index 0..7... (4 grp x 2c)
                bh[q][c] = *(const f16x8*)(buf + gl_ * 1024 + lane * 16);
                bl[q][c] = *(const f16x8*)(buf + 8192 + gl_ * 1024 + lane * 16);
            }

        __builtin_amdgcn_s_setprio(1);
        #pragma unroll
        for (int q = 0; q < 2; q++) {
            int code = t * 64 + ch * 32 + q * 16 + l15;
            #pragma unroll
            for (int s = 0; s < 2; s++) {
                f32x4 a2 = {ccv[q], ccv[q], ccv[q], ccv[q]};
                a2 = MFMA16(ah[s][0], bh[q][0], a2);
                a2 = MFMA16(ah[s][1], bh[q][1], a2);
                a2 = MFMA16(ah[s][0], bl[q][0], a2);
                a2 = MFMA16(ah[s][1], bl[q][1], a2);
                a2 = MFMA16(al[s][0], bh[q][0], a2);
                a2 = MFMA16(al[s][1], bh[q][1], a2);
                #pragma unroll
                for (int r = 0; r < 4; r++) {
                    if (a2[r] > bmax[s][r]) { bmax[s][r] = a2[r]; bix[s][r] = code; }
                }
            }
        }
        __builtin_amdgcn_s_setprio(0);

        // counted wait: outstanding after STAGE(t+3) = tiles t+1,t+2,t+3 (6 loads);
        // vmcnt(4) => tile t+1's 2 loads landed. Never drains to 0 in-loop (T4).
        asm volatile("s_waitcnt vmcnt(4)" ::: "memory");
        asm volatile("s_barrier" ::: "memory");
        __builtin_amdgcn_sched_barrier(0);
    }

    __syncthreads();   // final drain before reusing ring LDS for reduce

    // ---- argmax reduce: 16 code-lanes, then the 2 code-half waves per row
    float* redd = (float*)sm;            // [128][2]
    int*   redi = (int*)(sm + 1024);     // [128][2]
    int*   bidx = (int*)(sm + 2048);     // [128]
    #pragma unroll
    for (int s = 0; s < 2; s++)
        #pragma unroll
        for (int r = 0; r < 4; r++) {
            float d = bmax[s][r];
            int   ix = bix[s][r];
            #pragma unroll
            for (int m = 1; m < 16; m <<= 1) {
                float od = __shfl_xor(d, m);
                int   oi = __shfl_xor(ix, m);
                if (od > d || (od == d && oi < ix)) { d = od; ix = oi; }
            }
            if (l15 == 0) {
                int row = rg * 32 + s * 16 + l4 * 4 + r;
                redd[row * 2 + ch] = d;
                redi[row * 2 + ch] = ix;
            }
        }
    __syncthreads();
    if (tid < 128) {
        float d0 = redd[tid * 2 + 0];
        int   i0 = redi[tid * 2 + 0];
        float d1 = redd[tid * 2 + 1];
        int   i1 = redi[tid * 2 + 1];
        float bv = d0; int bi_ = i0;   // half 0 = lower codes: wins ties
        if (d1 > bv || (d1 == bv && i1 < bi_)) { bv = d1; bi_ = i1; }
        bidx[tid] = bi_;
        out[OUT2 + rowbase + tid] = (float)bi_;
    }
    __syncthreads();
    {   // gather cb32[best] -> chunk0 and chunk3
        int r = tid >> 2, seg = tid & 3;
        int ix = bidx[r];
        const float4* src = (const float4*)(cb32 + (long)ix * DIM + seg * 16);
        float4* o0 = (float4*)(out + (rowbase + r) * DIM + seg * 16);
        float4* o3 = (float4*)(out + OUT3 + (rowbase + r) * DIM + seg * 16);
        #pragma unroll
        for (int i = 0; i < 4; i++) { float4 t4 = src[i]; o0[i] = t4; o3[i] = t4; }
    }
}

extern "C" void kernel_launch(void* const* d_in, const int* in_sizes, int n_in,
                              void* d_out, int out_size, void* d_ws, size_t ws_size,
                              hipStream_t stream) {
    const float* z   = (const float*)d_in[0];
    const float* w   = (const float*)d_in[1];
    const float* bnw = (const float*)d_in[2];
    const float* bnb = (const float*)d_in[3];
    float* out = (float*)d_out;
    char*  wsb = (char*)d_ws;

    k_bn1 <<<64,  256, 0, stream>>>(w, wsb);
    k_cb  <<<256, 256, 0, stream>>>(w, bnw, bnb, wsb);
    k_main<<<256, 512, 0, stream>>>(z, wsb, out);
}